// Round 2
// baseline (1487.085 us; speedup 1.0000x reference)
//
#include <hip/hip_runtime.h>

#define EDGES 200000
#define NATOMS 100000
#define NMOLS 2000
#define H 128
#define MAXNB 15
#define AFD 18
#define INFD 23

typedef unsigned short bf16s;

__device__ inline float bf2f(bf16s u) {
  union { unsigned int i; float f; } c; c.i = ((unsigned int)u) << 16; return c.f;
}
__device__ inline bf16s f2bf(float f) {
  union { float f; unsigned int i; } c; c.f = f;
  unsigned int lsb = (c.i >> 16) & 1u;
  c.i += 0x7fffu + lsb;              // round-to-nearest-even
  return (bf16s)(c.i >> 16);
}

__device__ inline void load4(const float* p, float v[4]) {
  float4 t = *(const float4*)p; v[0] = t.x; v[1] = t.y; v[2] = t.z; v[3] = t.w;
}
__device__ inline void load4(const bf16s* p, float v[4]) {
  ushort4 t = *(const ushort4*)p;
  v[0] = bf2f(t.x); v[1] = bf2f(t.y); v[2] = bf2f(t.z); v[3] = bf2f(t.w);
}
__device__ inline void store4(float* p, const float v[4]) {
  *(float4*)p = make_float4(v[0], v[1], v[2], v[3]);
}
__device__ inline void store4(bf16s* p, const float v[4]) {
  ushort4 t; t.x = f2bf(v[0]); t.y = f2bf(v[1]); t.z = f2bf(v[2]); t.w = f2bf(v[3]);
  *(ushort4*)p = t;
}

// ---------------- binput = fbonds @ W_i ; message = relu(binput) ----------------
// 256 threads = 8 edges x 32 lanes; each lane computes 4 consecutive columns.
template <typename T>
__global__ __launch_bounds__(256) void k_binput(
    const float* __restrict__ fbonds, const float* __restrict__ Wi,
    T* __restrict__ binput, T* __restrict__ message) {
  __shared__ float Wl[INFD * H];
  const int tid = threadIdx.x;
  for (int i = tid; i < INFD * H; i += 256) Wl[i] = Wi[i];
  __syncthreads();
  const int lane = tid & 31;
  const int e = blockIdx.x * 8 + (tid >> 5);
  const float* fb = &fbonds[(size_t)e * INFD];
  float acc[4] = {0.f, 0.f, 0.f, 0.f};
#pragma unroll
  for (int k = 0; k < INFD; ++k) {
    float f = fb[k];
    float4 w = *(const float4*)&Wl[k * H + lane * 4];
    acc[0] = fmaf(f, w.x, acc[0]); acc[1] = fmaf(f, w.y, acc[1]);
    acc[2] = fmaf(f, w.z, acc[2]); acc[3] = fmaf(f, w.w, acc[3]);
  }
  store4(&binput[(size_t)e * H + lane * 4], acc);
  float r[4] = {fmaxf(acc[0], 0.f), fmaxf(acc[1], 0.f),
                fmaxf(acc[2], 0.f), fmaxf(acc[3], 0.f)};
  store4(&message[(size_t)e * H + lane * 4], r);
}

// ---------------- C[nrows,128] = A[nrows,128] @ W[128,128] ----------------
#define GT_ROWS 256
#define GK 16
#define AL_STRIDE (GT_ROWS + 4)

template <typename T>
__global__ __launch_bounds__(256, 2) void k_gemm_h(
    const T* __restrict__ A, const float* __restrict__ Wg,
    T* __restrict__ C, int nrows) {
  __shared__ float Wl[128 * 64];
  __shared__ float Al[GK * AL_STRIDE];
  const int tid = threadIdx.x;
  const int tile = blockIdx.x >> 1;
  const int ch = blockIdx.x & 1;
  const int row0 = tile * GT_ROWS;
#pragma unroll
  for (int i = 0; i < 8; ++i) {
    int idx = tid + 256 * i;
    int k = idx >> 4, j = (idx & 15) << 2;
    *(float4*)&Wl[k * 64 + j] = *(const float4*)&Wg[k * H + ch * 64 + j];
  }
  const int trow = tid >> 4, tcol = tid & 15;
  const int r0 = trow * 16;
  const int c0 = tcol * 4;
  float acc[16][4];
#pragma unroll
  for (int i = 0; i < 16; ++i)
#pragma unroll
    for (int j = 0; j < 4; ++j) acc[i][j] = 0.f;

  for (int ks = 0; ks < H / GK; ++ks) {
    const int kbase = ks * GK;
    float v[4][4];
#pragma unroll
    for (int i = 0; i < 4; ++i) {
      int idx = tid + 256 * i;
      int row = idx >> 2;
      int kb = (idx & 3) << 2;
      int grow = row0 + row;
      if (grow < nrows) load4(&A[(size_t)grow * H + kbase + kb], v[i]);
      else { v[i][0] = v[i][1] = v[i][2] = v[i][3] = 0.f; }
    }
    __syncthreads();
#pragma unroll
    for (int i = 0; i < 4; ++i) {
      int idx = tid + 256 * i;
      int row = idx >> 2;
      int kb = (idx & 3) << 2;
      Al[(kb + 0) * AL_STRIDE + row] = v[i][0];
      Al[(kb + 1) * AL_STRIDE + row] = v[i][1];
      Al[(kb + 2) * AL_STRIDE + row] = v[i][2];
      Al[(kb + 3) * AL_STRIDE + row] = v[i][3];
    }
    __syncthreads();
#pragma unroll
    for (int k = 0; k < GK; ++k) {
      float a[16], w[4];
      *(float4*)&a[0]  = *(const float4*)&Al[k * AL_STRIDE + r0];
      *(float4*)&a[4]  = *(const float4*)&Al[k * AL_STRIDE + r0 + 4];
      *(float4*)&a[8]  = *(const float4*)&Al[k * AL_STRIDE + r0 + 8];
      *(float4*)&a[12] = *(const float4*)&Al[k * AL_STRIDE + r0 + 12];
      *(float4*)&w[0]  = *(const float4*)&Wl[(kbase + k) * 64 + c0];
#pragma unroll
      for (int i = 0; i < 16; ++i)
#pragma unroll
        for (int j = 0; j < 4; ++j) acc[i][j] = fmaf(a[i], w[j], acc[i][j]);
    }
  }
#pragma unroll
  for (int i = 0; i < 16; ++i) {
    int row = row0 + r0 + i;
    if (row < nrows) store4(&C[(size_t)row * H + ch * 64 + c0], acc[i]);
  }
}

// ------------- message' = relu(binput + sum_j msgW[bgraph[e][j]]) -------------
template <typename T>
__global__ __launch_bounds__(256) void k_gather_relu(
    const int* __restrict__ bgraph, const T* __restrict__ msgW,
    const T* __restrict__ binput, T* __restrict__ out) {
  const int tid = threadIdx.x;
  const int lane = tid & 31;
  const int e = blockIdx.x * 8 + (tid >> 5);
  int idx[MAXNB];
#pragma unroll
  for (int j = 0; j < MAXNB; ++j) idx[j] = bgraph[e * MAXNB + j];
  float acc[4];
  load4(&binput[(size_t)e * H + lane * 4], acc);
#pragma unroll
  for (int j = 0; j < MAXNB; ++j) {
    float t[4];
    load4(&msgW[(size_t)idx[j] * H + lane * 4], t);
    acc[0] += t[0]; acc[1] += t[1]; acc[2] += t[2]; acc[3] += t[3];
  }
  acc[0] = fmaxf(acc[0], 0.f); acc[1] = fmaxf(acc[1], 0.f);
  acc[2] = fmaxf(acc[2], 0.f); acc[3] = fmaxf(acc[3], 0.f);
  store4(&out[(size_t)e * H + lane * 4], acc);
}

// atom_hiddens = relu(fatoms @ Wo[0:18] + sum_j msgWo[agraph[a][j]] + b_o)
template <typename T>
__global__ __launch_bounds__(256) void k_atoms(
    const float* __restrict__ fatoms, const int* __restrict__ agraph,
    const T* __restrict__ msgWo, const float* __restrict__ Wo,
    const float* __restrict__ bo, float* __restrict__ atomh) {
  __shared__ float Wl[AFD * H];
  const int tid = threadIdx.x;
  for (int i = tid; i < AFD * H; i += 256) Wl[i] = Wo[i];
  __syncthreads();
  const int lane = tid & 31;
  const int a = blockIdx.x * 8 + (tid >> 5);
  float4 b = ((const float4*)bo)[lane];
  float acc[4] = {b.x, b.y, b.z, b.w};
#pragma unroll
  for (int k = 0; k < AFD; ++k) {
    float f = fatoms[(size_t)a * AFD + k];
    float4 w = *(const float4*)&Wl[k * H + lane * 4];
    acc[0] = fmaf(f, w.x, acc[0]); acc[1] = fmaf(f, w.y, acc[1]);
    acc[2] = fmaf(f, w.z, acc[2]); acc[3] = fmaf(f, w.w, acc[3]);
  }
  int idx[MAXNB];
#pragma unroll
  for (int j = 0; j < MAXNB; ++j) idx[j] = agraph[a * MAXNB + j];
#pragma unroll
  for (int j = 0; j < MAXNB; ++j) {
    float t[4];
    load4(&msgWo[(size_t)idx[j] * H + lane * 4], t);
    acc[0] += t[0]; acc[1] += t[1]; acc[2] += t[2]; acc[3] += t[3];
  }
  float r[4] = {fmaxf(acc[0], 0.f), fmaxf(acc[1], 0.f),
                fmaxf(acc[2], 0.f), fmaxf(acc[3], 0.f)};
  *(float4*)&atomh[(size_t)a * H + lane * 4] = make_float4(r[0], r[1], r[2], r[3]);
}

// ---------------- segment mean pool ----------------
__global__ void k_pool(const float* __restrict__ atomh,
                       const int* __restrict__ sstart, const int* __restrict__ slen,
                       float* __restrict__ out) {
  const int m = blockIdx.x;
  const int c = threadIdx.x;
  const int s = sstart[m];
  const int L = slen[m];
  float sum = 0.f;
  for (int i = 0; i < L; ++i) sum += atomh[(size_t)(s + i) * H + c];
  out[m * H + c] = sum / (float)L;
}

template <typename T>
static void run_all(const float* fatoms, const float* fbonds, const int* agraph,
                    const int* bgraph, const int* sstart, const int* slen,
                    const float* Wi, const float* Wh, const float* Wo,
                    const float* bo, float* out, void* d_ws, hipStream_t stream) {
  const size_t EH = (size_t)EDGES * H;
  T* binput = (T*)d_ws;
  T* message = binput + EH;
  T* msgW = message + EH;
  float* atomh = (float*)d_ws;  // overlays binput region (dead after last gather)

  k_binput<T><<<EDGES / 8, 256, 0, stream>>>(fbonds, Wi, binput, message);
  const int gtiles = (EDGES + GT_ROWS - 1) / GT_ROWS;
  for (int d = 0; d < 5; ++d) {
    k_gemm_h<T><<<gtiles * 2, 256, 0, stream>>>(message, Wh, msgW, EDGES);
    k_gather_relu<T><<<EDGES / 8, 256, 0, stream>>>(bgraph, msgW, binput, message);
  }
  k_gemm_h<T><<<gtiles * 2, 256, 0, stream>>>(message, Wo + AFD * H, msgW, EDGES);
  k_atoms<T><<<NATOMS / 8, 256, 0, stream>>>(fatoms, agraph, msgW, Wo, bo, atomh);
  k_pool<<<NMOLS, H, 0, stream>>>(atomh, sstart, slen, out);
}

extern "C" void kernel_launch(void* const* d_in, const int* in_sizes, int n_in,
                              void* d_out, int out_size, void* d_ws, size_t ws_size,
                              hipStream_t stream) {
  const float* fatoms = (const float*)d_in[0];
  const float* fbonds = (const float*)d_in[1];
  const int* agraph = (const int*)d_in[2];
  const int* bgraph = (const int*)d_in[3];
  const int* sstart = (const int*)d_in[4];
  const int* slen = (const int*)d_in[5];
  const float* Wi = (const float*)d_in[6];
  const float* Wh = (const float*)d_in[7];
  const float* Wo = (const float*)d_in[8];
  const float* bo = (const float*)d_in[9];
  float* out = (float*)d_out;

  const size_t EH = (size_t)EDGES * H;
  if (ws_size >= 3 * EH * sizeof(float)) {
    run_all<float>(fatoms, fbonds, agraph, bgraph, sstart, slen,
                   Wi, Wh, Wo, bo, out, d_ws, stream);
  } else {
    run_all<bf16s>(fatoms, fbonds, agraph, bgraph, sstart, slen,
                   Wi, Wh, Wo, bo, out, d_ws, stream);
  }
}

// Round 3
// 1162.704 us; speedup vs baseline: 1.2790x; 1.2790x over previous
//
#include <hip/hip_runtime.h>

#define EDGES 200000
#define NATOMS 100000
#define NMOLS 2000
#define H 128
#define MAXNB 15
#define AFD 18
#define INFD 23

typedef unsigned short bf16s;
typedef __attribute__((ext_vector_type(8))) short short8;
typedef __attribute__((ext_vector_type(4))) float f32x4;

__device__ inline float bf2f(bf16s u) {
  union { unsigned int i; float f; } c; c.i = ((unsigned int)u) << 16; return c.f;
}
__device__ inline bf16s f2bf(float f) {
  union { float f; unsigned int i; } c; c.f = f;
  unsigned int lsb = (c.i >> 16) & 1u;
  c.i += 0x7fffu + lsb;              // round-to-nearest-even
  return (bf16s)(c.i >> 16);
}

__device__ inline void load4(const bf16s* p, float v[4]) {
  ushort4 t = *(const ushort4*)p;
  v[0] = bf2f(t.x); v[1] = bf2f(t.y); v[2] = bf2f(t.z); v[3] = bf2f(t.w);
}
__device__ inline void store4(bf16s* p, const float v[4]) {
  ushort4 t; t.x = f2bf(v[0]); t.y = f2bf(v[1]); t.z = f2bf(v[2]); t.w = f2bf(v[3]);
  *(ushort4*)p = t;
}

// ------- one-time: Wt[n][k] = bf16(W[k][n]) for W_h and W_o[AFD:,:] -------
__global__ __launch_bounds__(256) void k_wt(
    const float* __restrict__ Wh, const float* __restrict__ Wo,
    bf16s* __restrict__ wt_h, bf16s* __restrict__ wt_o) {
  const float* S = blockIdx.x ? (Wo + AFD * H) : Wh;
  bf16s* D = blockIdx.x ? wt_o : wt_h;
  for (int i = threadIdx.x; i < H * H; i += 256) {
    int k = i >> 7, n = i & 127;
    D[n * H + k] = f2bf(S[i]);
  }
}

// ---------------- binput = fbonds @ W_i ; message = relu(binput) ----------------
__global__ __launch_bounds__(256) void k_binput(
    const float* __restrict__ fbonds, const float* __restrict__ Wi,
    bf16s* __restrict__ binput, bf16s* __restrict__ message) {
  __shared__ float Wl[INFD * H];
  const int tid = threadIdx.x;
  for (int i = tid; i < INFD * H; i += 256) Wl[i] = Wi[i];
  __syncthreads();
  const int lane = tid & 31;
  const int e = blockIdx.x * 8 + (tid >> 5);
  const float* fb = &fbonds[(size_t)e * INFD];
  float acc[4] = {0.f, 0.f, 0.f, 0.f};
#pragma unroll
  for (int k = 0; k < INFD; ++k) {
    float f = fb[k];
    float4 w = *(const float4*)&Wl[k * H + lane * 4];
    acc[0] = fmaf(f, w.x, acc[0]); acc[1] = fmaf(f, w.y, acc[1]);
    acc[2] = fmaf(f, w.z, acc[2]); acc[3] = fmaf(f, w.w, acc[3]);
  }
  store4(&binput[(size_t)e * H + lane * 4], acc);
  float r[4] = {fmaxf(acc[0], 0.f), fmaxf(acc[1], 0.f),
                fmaxf(acc[2], 0.f), fmaxf(acc[3], 0.f)};
  store4(&message[(size_t)e * H + lane * 4], r);
}

// ---------------- C[E,128] = A[E,128] @ W, MFMA bf16, no LDS ----------------
// Block = 4 waves x 16 rows = 64 rows. Wave: 1 m-tile x 8 n-tiles, K=128.
// A-frag:  A[m=lane&15][k=quad*8+j]  -> 16B contiguous per lane from A.
// B-frag:  B[k=quad*8+j][n=lane&15]  -> 16B contiguous per lane from Wt[n][k].
// D:       row=quad*4+reg, col=lane&15.
__global__ __launch_bounds__(256) void k_gemm_mfma(
    const bf16s* __restrict__ A, const bf16s* __restrict__ Wt,
    bf16s* __restrict__ C) {
  const int wave = threadIdx.x >> 6;
  const int lane = threadIdx.x & 63;
  const int m = lane & 15;
  const int quad = lane >> 4;
  const int row0 = blockIdx.x * 64 + wave * 16;

  f32x4 acc[8];
#pragma unroll
  for (int i = 0; i < 8; ++i) acc[i] = (f32x4){0.f, 0.f, 0.f, 0.f};

  const bf16s* Ap = A + (size_t)(row0 + m) * H + quad * 8;
  const bf16s* Wp = Wt + (size_t)m * H + quad * 8;

#pragma unroll
  for (int kk = 0; kk < 4; ++kk) {
    short8 af = *(const short8*)(Ap + kk * 32);
#pragma unroll
    for (int nt = 0; nt < 8; ++nt) {
      short8 bfr = *(const short8*)(Wp + (size_t)(nt * 16) * H + kk * 32);
      acc[nt] = __builtin_amdgcn_mfma_f32_16x16x32_bf16(af, bfr, acc[nt], 0, 0, 0);
    }
  }
  const int rbase = row0 + quad * 4;
#pragma unroll
  for (int nt = 0; nt < 8; ++nt) {
#pragma unroll
    for (int i = 0; i < 4; ++i) {
      C[(size_t)(rbase + i) * H + nt * 16 + m] = f2bf(acc[nt][i]);
    }
  }
}

// ------------- message' = relu(binput + sum_j msgW[bgraph[e][j]]) -------------
__global__ __launch_bounds__(256) void k_gather_relu(
    const int* __restrict__ bgraph, const bf16s* __restrict__ msgW,
    const bf16s* __restrict__ binput, bf16s* __restrict__ out) {
  const int tid = threadIdx.x;
  const int lane = tid & 31;
  const int e = blockIdx.x * 8 + (tid >> 5);
  int idx[MAXNB];
#pragma unroll
  for (int j = 0; j < MAXNB; ++j) idx[j] = bgraph[e * MAXNB + j];
  float acc[4];
  load4(&binput[(size_t)e * H + lane * 4], acc);
#pragma unroll
  for (int j = 0; j < MAXNB; ++j) {
    float t[4];
    load4(&msgW[(size_t)idx[j] * H + lane * 4], t);
    acc[0] += t[0]; acc[1] += t[1]; acc[2] += t[2]; acc[3] += t[3];
  }
  acc[0] = fmaxf(acc[0], 0.f); acc[1] = fmaxf(acc[1], 0.f);
  acc[2] = fmaxf(acc[2], 0.f); acc[3] = fmaxf(acc[3], 0.f);
  store4(&out[(size_t)e * H + lane * 4], acc);
}

// atom_hiddens = relu(fatoms @ Wo[0:18] + sum_j msgWo[agraph[a][j]] + b_o)
__global__ __launch_bounds__(256) void k_atoms(
    const float* __restrict__ fatoms, const int* __restrict__ agraph,
    const bf16s* __restrict__ msgWo, const float* __restrict__ Wo,
    const float* __restrict__ bo, float* __restrict__ atomh) {
  __shared__ float Wl[AFD * H];
  const int tid = threadIdx.x;
  for (int i = tid; i < AFD * H; i += 256) Wl[i] = Wo[i];
  __syncthreads();
  const int lane = tid & 31;
  const int a = blockIdx.x * 8 + (tid >> 5);
  float4 b = ((const float4*)bo)[lane];
  float acc[4] = {b.x, b.y, b.z, b.w};
#pragma unroll
  for (int k = 0; k < AFD; ++k) {
    float f = fatoms[(size_t)a * AFD + k];
    float4 w = *(const float4*)&Wl[k * H + lane * 4];
    acc[0] = fmaf(f, w.x, acc[0]); acc[1] = fmaf(f, w.y, acc[1]);
    acc[2] = fmaf(f, w.z, acc[2]); acc[3] = fmaf(f, w.w, acc[3]);
  }
  int idx[MAXNB];
#pragma unroll
  for (int j = 0; j < MAXNB; ++j) idx[j] = agraph[a * MAXNB + j];
#pragma unroll
  for (int j = 0; j < MAXNB; ++j) {
    float t[4];
    load4(&msgWo[(size_t)idx[j] * H + lane * 4], t);
    acc[0] += t[0]; acc[1] += t[1]; acc[2] += t[2]; acc[3] += t[3];
  }
  float r[4] = {fmaxf(acc[0], 0.f), fmaxf(acc[1], 0.f),
                fmaxf(acc[2], 0.f), fmaxf(acc[3], 0.f)};
  *(float4*)&atomh[(size_t)a * H + lane * 4] = make_float4(r[0], r[1], r[2], r[3]);
}

// ---------------- segment mean pool ----------------
__global__ void k_pool(const float* __restrict__ atomh,
                       const int* __restrict__ sstart, const int* __restrict__ slen,
                       float* __restrict__ out) {
  const int m = blockIdx.x;
  const int c = threadIdx.x;
  const int s = sstart[m];
  const int L = slen[m];
  float sum = 0.f;
  for (int i = 0; i < L; ++i) sum += atomh[(size_t)(s + i) * H + c];
  out[m * H + c] = sum / (float)L;
}

extern "C" void kernel_launch(void* const* d_in, const int* in_sizes, int n_in,
                              void* d_out, int out_size, void* d_ws, size_t ws_size,
                              hipStream_t stream) {
  const float* fatoms = (const float*)d_in[0];
  const float* fbonds = (const float*)d_in[1];
  const int* agraph = (const int*)d_in[2];
  const int* bgraph = (const int*)d_in[3];
  const int* sstart = (const int*)d_in[4];
  const int* slen = (const int*)d_in[5];
  const float* Wi = (const float*)d_in[6];
  const float* Wh = (const float*)d_in[7];
  const float* Wo = (const float*)d_in[8];
  const float* bo = (const float*)d_in[9];
  float* out = (float*)d_out;

  const size_t EH = (size_t)EDGES * H;
  bf16s* binput = (bf16s*)d_ws;          // [E,H] bf16, 51.2 MB
  bf16s* message = binput + EH;          // [E,H] bf16
  bf16s* msgW = message + EH;            // [E,H] bf16
  float* atomh = (float*)d_ws;           // overlays binput (dead after last gather)
  // stash bf16-transposed weights in d_out; k_pool fully overwrites it at the end
  bf16s* wt_h = (bf16s*)d_out;           // [H,H] bf16, 32 KB
  bf16s* wt_o = wt_h + H * H;            // [H,H] bf16, 32 KB

  k_wt<<<2, 256, 0, stream>>>(Wh, Wo, wt_h, wt_o);
  k_binput<<<EDGES / 8, 256, 0, stream>>>(fbonds, Wi, binput, message);
  for (int d = 0; d < 5; ++d) {
    k_gemm_mfma<<<EDGES / 64, 256, 0, stream>>>(message, wt_h, msgW);
    k_gather_relu<<<EDGES / 8, 256, 0, stream>>>(bgraph, msgW, binput, message);
  }
  k_gemm_mfma<<<EDGES / 64, 256, 0, stream>>>(message, wt_o, msgW);
  k_atoms<<<NATOMS / 8, 256, 0, stream>>>(fatoms, agraph, msgW, Wo, bo, atomh);
  k_pool<<<NMOLS, H, 0, stream>>>(atomh, sstart, slen, out);
}